// Round 4
// baseline (289.331 us; speedup 1.0000x reference)
//
#include <hip/hip_runtime.h>

#define H 32
#define Q 64
#define S 8192
#define D 128
#define OBS 16
#define L 2048

typedef float f32x4 __attribute__((ext_vector_type(4)));

// Kernel 1: fused priority + exact top-L select. One 1024-thread block per head.
// Reads this head's last-OBS attn rows directly (512 KB, 4 independent
// accumulator chains for MLP), computes priority into LDS, then the verified
// 4-pass byte-histogram select with all pass-histograms pre-zeroed once.
// pos_out is written by the gather kernel (coalesced there, scattered here).
__global__ __launch_bounds__(1024) void k_priosel(
    const float* __restrict__ attn,
    int* __restrict__ keep,
    float* __restrict__ hist_out)
{
    __shared__ float pr[S];            // 32 KB priority row
    __shared__ int whist[4][16][257];  // per-pass per-wave histograms
    __shared__ int wtot[16];
    __shared__ int res_byte, res_k;

    const int h = blockIdx.x;
    const int tid = threadIdx.x;
    const int lane = tid & 63, wid = tid >> 6;

    // ---- zero all 4 pass-histograms (overlaps with attn loads below) ----
    for (int i = tid; i < 4 * 16 * 257; i += 1024) ((int*)whist)[i] = 0;

    // ---- priority: mean of last OBS attn rows, directly from global ----
    {
        const float* abase = attn + (size_t)(h * Q + (Q - OBS)) * S;
        f32x4 a00 = {0.f, 0.f, 0.f, 0.f}, a01 = a00, a10 = a00, a11 = a00;
#pragma unroll
        for (int q = 0; q < OBS; q += 2) {
            const f32x4* r0 = (const f32x4*)(abase + (size_t)q * S);
            const f32x4* r1 = (const f32x4*)(abase + (size_t)(q + 1) * S);
            a00 += __builtin_nontemporal_load(r0 + tid);
            a01 += __builtin_nontemporal_load(r0 + tid + 1024);
            a10 += __builtin_nontemporal_load(r1 + tid);
            a11 += __builtin_nontemporal_load(r1 + tid + 1024);
        }
        const float inv = 1.0f / (float)OBS;
        ((f32x4*)pr)[tid] = (a00 + a10) * inv;
        ((f32x4*)pr)[tid + 1024] = (a01 + a11) * inv;
    }
    __syncthreads();

    // ---- pooled keys (positive floats -> monotone uint bits) ----
    unsigned key[8];
    const int s0 = tid * 8;
    {
        float w[12];
#pragma unroll
        for (int i = 0; i < 12; ++i) {
            int idx = s0 - 2 + i;
            w[i] = (idx >= 0 && idx < S) ? pr[idx] : 0.f;
        }
#pragma unroll
        for (int j = 0; j < 8; ++j) {
            int s = s0 + j;
            float pooled;
            if (s >= S - OBS) {
                pooled = 1.0f;
            } else {
                int lo = s - 2; if (lo < 0) lo = 0;
                int hi = s + 3;
                float sum = 0.f;
                for (int i = lo; i < hi; ++i) sum += w[i - s0 + 2];
                pooled = sum / (float)(hi - lo);
            }
            key[j] = __float_as_uint(pooled);
        }
    }

    // ---- 4-pass byte-histogram top-L select (2 barriers/pass) ----
    unsigned prefix = 0;
    int k = L;
    for (int pass = 3; pass >= 0; --pass) {
        const int shift = pass * 8;
        {
            int cur = -1, run = 0;
#pragma unroll
            for (int j = 0; j < 8; ++j) {
                unsigned kk = key[j];
                bool match = (pass == 3) || ((kk >> (shift + 8)) == prefix);
                int b = match ? (int)((kk >> shift) & 255u) : -1;
                if (b != cur) {
                    if (cur >= 0) atomicAdd(&whist[pass][wid][cur], run);
                    cur = b; run = 1;
                } else {
                    run++;
                }
            }
            if (cur >= 0) atomicAdd(&whist[pass][wid][cur], run);
        }
        __syncthreads();
        if (wid == 0) {
            int b0 = 0, b1 = 0, b2 = 0, b3 = 0;
            const int bb0 = 4 * lane;
#pragma unroll
            for (int w = 0; w < 16; ++w) {
                b0 += whist[pass][w][bb0 + 0];
                b1 += whist[pass][w][bb0 + 1];
                b2 += whist[pass][w][bb0 + 2];
                b3 += whist[pass][w][bb0 + 3];
            }
            int lane_sum = b0 + b1 + b2 + b3;
            int suffix = lane_sum;   // inclusive suffix over lanes
#pragma unroll
            for (int off = 1; off < 64; off <<= 1) {
                int u = __shfl_down(suffix, off);
                if (lane + off < 64) suffix += u;
            }
            int suffix_next = suffix - lane_sum;
            if (suffix >= k && suffix_next < k) {
                int bins[4] = {b0, b1, b2, b3};
                int cum = suffix_next;
                for (int bb = 3; bb >= 0; --bb) {
                    int nc = cum + bins[bb];
                    if (nc >= k) { res_byte = bb0 + bb; res_k = k - cum; break; }
                    cum = nc;
                }
            }
        }
        __syncthreads();
        prefix = (prefix << 8) | (unsigned)res_byte;
        k = res_k;
    }
    const unsigned T = prefix;
    const int needed_eq = k;

    // ---- single packed (gt,eq) scan -> output ranks ----
    int gt = 0, eq = 0;
#pragma unroll
    for (int j = 0; j < 8; ++j) {
        gt += (key[j] > T) ? 1 : 0;
        eq += (key[j] == T) ? 1 : 0;
    }
    int packed = (gt << 16) | eq;
    int v = packed;
#pragma unroll
    for (int off = 1; off < 64; off <<= 1) {
        int u = __shfl_up(v, off);
        if (lane >= off) v += u;
    }
    if (lane == 63) wtot[wid] = v;
    __syncthreads();
    int base = 0;
    for (int w = 0; w < wid; ++w) base += wtot[w];
    int excl = base + v - packed;
    int gt_before = excl >> 16;
    int eq_before = excl & 0xffff;

    // ---- epilogue: scattered writes in index order (already sorted) ----
    {
        int g = gt_before, e = eq_before;
#pragma unroll
        for (int j = 0; j < 8; ++j) {
            bool isgt = key[j] > T;
            bool iseq = key[j] == T;
            bool sel = isgt || (iseq && (e < needed_eq));
            if (sel) {
                int s = s0 + j;
                int rank = g + (e < needed_eq ? e : needed_eq);
                size_t o = (size_t)h * L + rank;
                keep[o] = s;
                hist_out[o] = pr[s];
            }
            g += isgt ? 1 : 0;
            e += iseq ? 1 : 0;
        }
    }
}

// Kernel 2: gather selected K/V rows + coalesced pos write. 2048 blocks x 256
// threads (8 blocks/CU); each 32-lane group handles 4 consecutive ranks: one
// broadcast int4 keep-load, then 8 independent 512B row copies in flight
// (nontemporal: streamed, no reuse).
__global__ void k_gather(const float* __restrict__ kv_k, const float* __restrict__ kv_v,
                         const int* __restrict__ keep, float* __restrict__ out,
                         float* __restrict__ pos_out) {
    const int tid = threadIdx.x;
    const int l32 = tid & 31;
    const int i0 = (blockIdx.x * 8 + (tid >> 5)) * 4;   // h*L + rank, 4-aligned
    const int h = i0 >> 11;                             // same head for all 4
    const int4 kk = *(const int4*)(keep + i0);          // broadcast 16B load
    const int sI[4] = {kk.x, kk.y, kk.z, kk.w};
    if (l32 < 4) pos_out[i0 + l32] = (float)sI[l32];    // coalesced pos write
#pragma unroll
    for (int t = 0; t < 4; ++t) {
        const int idx = i0 + t;
        const f32x4* srcK = (const f32x4*)(kv_k + (size_t)(h * S + sI[t]) * D);
        const f32x4* srcV = (const f32x4*)(kv_v + (size_t)(h * S + sI[t]) * D);
        f32x4* dstK = (f32x4*)(out + (size_t)idx * D);
        f32x4* dstV = (f32x4*)(out + ((size_t)H * L + idx) * D);
        __builtin_nontemporal_store(__builtin_nontemporal_load(srcK + l32), dstK + l32);
        __builtin_nontemporal_store(__builtin_nontemporal_load(srcV + l32), dstV + l32);
    }
}

extern "C" void kernel_launch(void* const* d_in, const int* in_sizes, int n_in,
                              void* d_out, int out_size, void* d_ws, size_t ws_size,
                              hipStream_t stream) {
    const float* attn = (const float*)d_in[0];
    const float* k_val = (const float*)d_in[1];
    const float* v_val = (const float*)d_in[2];

    float* out = (float*)d_out;
    float* hist = out + (size_t)2 * H * L * D;
    float* pos = hist + (size_t)H * L;

    int* keep = (int*)d_ws;   // H*L ints, 16B-aligned

    k_priosel<<<H, 1024, 0, stream>>>(attn, keep, hist);
    k_gather<<<(H * L) / 32, 256, 0, stream>>>(k_val, v_val, keep, out, pos);
}

// Round 5
// 286.292 us; speedup vs baseline: 1.0106x; 1.0106x over previous
//
#include <hip/hip_runtime.h>

#define H 32
#define Q 64
#define S 8192
#define D 128
#define OBS 16
#define L 2048

typedef float f32x4 __attribute__((ext_vector_type(4)));

// Kernel 1: priority[h][s] = mean over last OBS queries of attn[0,h,q,s].
// Full-chip wide: 256 blocks (1/CU) so the 16 MiB attn read runs at HBM rate
// (~3 us) instead of the 32-CU request-rate limit (~21 us) of the fused form.
// 4 independent accumulator chains for MLP; nt loads (streamed, no reuse).
__global__ void k_priority(const float* __restrict__ attn, float* __restrict__ prio) {
    const int gid = blockIdx.x;            // 0..255
    const int h = gid >> 3;                // 32 heads
    const int chunk = gid & 7;             // 8 chunks of 1024 floats
    const int s4 = chunk * 1024 + threadIdx.x * 4;
    const f32x4* base = (const f32x4*)(attn + ((size_t)(h * Q + (Q - OBS)) * S + s4));
    f32x4 a0 = {0.f, 0.f, 0.f, 0.f}, a1 = a0, a2 = a0, a3 = a0;
#pragma unroll
    for (int q = 0; q < OBS; q += 4) {
        a0 += __builtin_nontemporal_load(base + (size_t)(q + 0) * (S / 4));
        a1 += __builtin_nontemporal_load(base + (size_t)(q + 1) * (S / 4));
        a2 += __builtin_nontemporal_load(base + (size_t)(q + 2) * (S / 4));
        a3 += __builtin_nontemporal_load(base + (size_t)(q + 3) * (S / 4));
    }
    const f32x4 r = (a0 + a1 + a2 + a3) * (1.0f / (float)OBS);
    *((f32x4*)(prio + (size_t)h * S + s4)) = r;   // cached store: select re-reads it
}

// Kernel 2: exact top-L select. One 1024-thread block per head. Loads the 32 KB
// priority row (L2/L3-hot), pools, then the verified 4-pass byte-histogram
// select with all pass-histograms pre-zeroed once (overlapped with the load).
// pos_out is written by the gather kernel (coalesced there, scattered here).
__global__ __launch_bounds__(1024) void k_select(
    const float* __restrict__ prio,
    int* __restrict__ keep,
    float* __restrict__ hist_out)
{
    __shared__ float pr[S];            // 32 KB priority row
    __shared__ int whist[4][16][257];  // per-pass per-wave histograms
    __shared__ int wtot[16];
    __shared__ int res_byte, res_k;

    const int h = blockIdx.x;
    const int tid = threadIdx.x;
    const int lane = tid & 63, wid = tid >> 6;

    // ---- zero all 4 pass-histograms + load priority row (overlapped) ----
    {
        const f32x4* src = (const f32x4*)(prio + (size_t)h * S);
        ((f32x4*)pr)[tid] = src[tid];
        ((f32x4*)pr)[tid + 1024] = src[tid + 1024];
        for (int i = tid; i < 4 * 16 * 257; i += 1024) ((int*)whist)[i] = 0;
    }
    __syncthreads();

    // ---- pooled keys (positive floats -> monotone uint bits) ----
    unsigned key[8];
    const int s0 = tid * 8;
    {
        float w[12];
#pragma unroll
        for (int i = 0; i < 12; ++i) {
            int idx = s0 - 2 + i;
            w[i] = (idx >= 0 && idx < S) ? pr[idx] : 0.f;
        }
#pragma unroll
        for (int j = 0; j < 8; ++j) {
            int s = s0 + j;
            float pooled;
            if (s >= S - OBS) {
                pooled = 1.0f;
            } else {
                int lo = s - 2; if (lo < 0) lo = 0;
                int hi = s + 3;
                float sum = 0.f;
                for (int i = lo; i < hi; ++i) sum += w[i - s0 + 2];
                pooled = sum / (float)(hi - lo);
            }
            key[j] = __float_as_uint(pooled);
        }
    }

    // ---- 4-pass byte-histogram top-L select (2 barriers/pass) ----
    unsigned prefix = 0;
    int k = L;
    for (int pass = 3; pass >= 0; --pass) {
        const int shift = pass * 8;
        {
            int cur = -1, run = 0;
#pragma unroll
            for (int j = 0; j < 8; ++j) {
                unsigned kk = key[j];
                bool match = (pass == 3) || ((kk >> (shift + 8)) == prefix);
                int b = match ? (int)((kk >> shift) & 255u) : -1;
                if (b != cur) {
                    if (cur >= 0) atomicAdd(&whist[pass][wid][cur], run);
                    cur = b; run = 1;
                } else {
                    run++;
                }
            }
            if (cur >= 0) atomicAdd(&whist[pass][wid][cur], run);
        }
        __syncthreads();
        if (wid == 0) {
            int b0 = 0, b1 = 0, b2 = 0, b3 = 0;
            const int bb0 = 4 * lane;
#pragma unroll
            for (int w = 0; w < 16; ++w) {
                b0 += whist[pass][w][bb0 + 0];
                b1 += whist[pass][w][bb0 + 1];
                b2 += whist[pass][w][bb0 + 2];
                b3 += whist[pass][w][bb0 + 3];
            }
            int lane_sum = b0 + b1 + b2 + b3;
            int suffix = lane_sum;   // inclusive suffix over lanes
#pragma unroll
            for (int off = 1; off < 64; off <<= 1) {
                int u = __shfl_down(suffix, off);
                if (lane + off < 64) suffix += u;
            }
            int suffix_next = suffix - lane_sum;
            if (suffix >= k && suffix_next < k) {
                int bins[4] = {b0, b1, b2, b3};
                int cum = suffix_next;
                for (int bb = 3; bb >= 0; --bb) {
                    int nc = cum + bins[bb];
                    if (nc >= k) { res_byte = bb0 + bb; res_k = k - cum; break; }
                    cum = nc;
                }
            }
        }
        __syncthreads();
        prefix = (prefix << 8) | (unsigned)res_byte;
        k = res_k;
    }
    const unsigned T = prefix;
    const int needed_eq = k;

    // ---- single packed (gt,eq) scan -> output ranks ----
    int gt = 0, eq = 0;
#pragma unroll
    for (int j = 0; j < 8; ++j) {
        gt += (key[j] > T) ? 1 : 0;
        eq += (key[j] == T) ? 1 : 0;
    }
    int packed = (gt << 16) | eq;
    int v = packed;
#pragma unroll
    for (int off = 1; off < 64; off <<= 1) {
        int u = __shfl_up(v, off);
        if (lane >= off) v += u;
    }
    if (lane == 63) wtot[wid] = v;
    __syncthreads();
    int base = 0;
    for (int w = 0; w < wid; ++w) base += wtot[w];
    int excl = base + v - packed;
    int gt_before = excl >> 16;
    int eq_before = excl & 0xffff;

    // ---- epilogue: scattered writes in index order (already sorted) ----
    {
        int g = gt_before, e = eq_before;
#pragma unroll
        for (int j = 0; j < 8; ++j) {
            bool isgt = key[j] > T;
            bool iseq = key[j] == T;
            bool sel = isgt || (iseq && (e < needed_eq));
            if (sel) {
                int s = s0 + j;
                int rank = g + (e < needed_eq ? e : needed_eq);
                size_t o = (size_t)h * L + rank;
                keep[o] = s;
                hist_out[o] = pr[s];
            }
            g += isgt ? 1 : 0;
            e += iseq ? 1 : 0;
        }
    }
}

// Kernel 3: gather selected K/V rows + coalesced pos write. 2048 blocks x 256
// threads (8 blocks/CU); each 32-lane group handles 4 consecutive ranks: one
// broadcast int4 keep-load, then 8 independent 512B row copies in flight
// (nontemporal: streamed, no reuse).
__global__ void k_gather(const float* __restrict__ kv_k, const float* __restrict__ kv_v,
                         const int* __restrict__ keep, float* __restrict__ out,
                         float* __restrict__ pos_out) {
    const int tid = threadIdx.x;
    const int l32 = tid & 31;
    const int i0 = (blockIdx.x * 8 + (tid >> 5)) * 4;   // h*L + rank, 4-aligned
    const int h = i0 >> 11;                             // same head for all 4
    const int4 kk = *(const int4*)(keep + i0);          // broadcast 16B load
    const int sI[4] = {kk.x, kk.y, kk.z, kk.w};
    if (l32 < 4) pos_out[i0 + l32] = (float)sI[l32];    // coalesced pos write
#pragma unroll
    for (int t = 0; t < 4; ++t) {
        const int idx = i0 + t;
        const f32x4* srcK = (const f32x4*)(kv_k + (size_t)(h * S + sI[t]) * D);
        const f32x4* srcV = (const f32x4*)(kv_v + (size_t)(h * S + sI[t]) * D);
        f32x4* dstK = (f32x4*)(out + (size_t)idx * D);
        f32x4* dstV = (f32x4*)(out + ((size_t)H * L + idx) * D);
        __builtin_nontemporal_store(__builtin_nontemporal_load(srcK + l32), dstK + l32);
        __builtin_nontemporal_store(__builtin_nontemporal_load(srcV + l32), dstV + l32);
    }
}

extern "C" void kernel_launch(void* const* d_in, const int* in_sizes, int n_in,
                              void* d_out, int out_size, void* d_ws, size_t ws_size,
                              hipStream_t stream) {
    const float* attn = (const float*)d_in[0];
    const float* k_val = (const float*)d_in[1];
    const float* v_val = (const float*)d_in[2];

    float* out = (float*)d_out;
    float* hist = out + (size_t)2 * H * L * D;
    float* pos = hist + (size_t)H * L;

    // ws layout: prio H*S floats (1 MiB) | keep H*L ints (16B-aligned)
    float* prio = (float*)d_ws;
    int* keep = (int*)((char*)d_ws + (size_t)H * S * sizeof(float));

    k_priority<<<256, 256, 0, stream>>>(attn, prio);
    k_select<<<H, 1024, 0, stream>>>(prio, keep, hist);
    k_gather<<<(H * L) / 32, 256, 0, stream>>>(k_val, v_val, keep, out, pos);
}